// Round 5
// baseline (841.730 us; speedup 1.0000x reference)
//
#include <hip/hip_runtime.h>

#define DEVINL static __device__ __forceinline__
// Same-wave LDS ordering: compiler reorder fence only (validated r10/r12).
#define CFENCE() asm volatile("" ::: "memory")

typedef float v2f __attribute__((ext_vector_type(2)));

DEVINL v2f mk2(float a, float b) { v2f r; r.x = a; r.y = b; return r; }
DEVINL v2f pkfma(v2f a, v2f b, v2f c) { return __builtin_elementwise_fma(a, b, c); }

constexpr float KE = 2.885390081777927f;   // 2*log2(e)

#if __has_builtin(__builtin_amdgcn_exp2f)
DEVINL float exp2_fast(float x) { return __builtin_amdgcn_exp2f(x); }
#else
DEVINL float exp2_fast(float x) { return __expf(x * 0.6931471805599453f); }
#endif

// tanh(x) with t = x*2*log2(e) pre-folded into weights: 1 - 2/(2^t+1).
DEVINL float tanh_pre(float t) {
  float e = exp2_fast(t);
  return 1.0f - 2.0f * __builtin_amdgcn_rcpf(e + 1.0f);
}

template <int CTRL>
DEVINL float dpp_add(float v) {
  int t = __builtin_amdgcn_update_dpp(0, __float_as_int(v), CTRL, 0xF, 0xF, true);
  return v + __int_as_float(t);
}
DEVINL float rlane(float v, int l) {
  return __int_as_float(__builtin_amdgcn_readlane(__float_as_int(v), l));
}
// Per-element 32-lane total via 4 row-local DPP stages + readlane pairs.
// Pure ALU (no LDS crossbar). row r sum lands in every lane of row r;
// elemA = rl(0)+rl(16), elemB = rl(32)+rl(48). Commutative pair-add ->
// bit-identical to the previous ds_swizzle xor16 version.
DEVINL float elem_total_sel(float v, bool hi) {
  v = dpp_add<0xB1>(v);    // quad_perm [1,0,3,2]
  v = dpp_add<0x4E>(v);    // quad_perm [2,3,0,1]
  v = dpp_add<0x141>(v);   // row_half_mirror
  v = dpp_add<0x140>(v);   // row_mirror -> 16-sums per 16-lane row
  float s0 = rlane(v, 0), s1 = rlane(v, 16);
  float s2 = rlane(v, 32), s3 = rlane(v, 48);
  float tA = s0 + s1;
  float tB = s2 + s3;
  return hi ? tB : tA;
}

// 32-wide dot vs an LDS row (uniform address per half), packed fp32.
DEVINL float dot32(const float* hrow, const v2f* W, float bias) {
  const float4* hp = (const float4*)hrow;
  v2f a0 = mk2(bias, 0.f), a1 = mk2(0.f, 0.f);
  v2f a2 = mk2(0.f, 0.f), a3 = mk2(0.f, 0.f);
#pragma unroll
  for (int q = 0; q < 8; q += 2) {
    float4 x = hp[q], y = hp[q + 1];
    a0 = pkfma(mk2(x.x, x.y), W[2 * q + 0], a0);
    a1 = pkfma(mk2(x.z, x.w), W[2 * q + 1], a1);
    a2 = pkfma(mk2(y.x, y.y), W[2 * q + 2], a2);
    a3 = pkfma(mk2(y.z, y.w), W[2 * q + 3], a3);
  }
  v2f s = (a0 + a1) + (a2 + a3);
  return s.x + s.y;
}

constexpr int TT = 256;

// wave = 2 batch elements: lanes 0-31 = element 2b, lanes 32-63 = 2b+1.
// Lane j handles neuron j of r1 AND r2 AND r3 for its element.
// grid 2048 -> 2 waves/EU; waves_per_eu(2,2) -> 256-VGPR budget.
// z-state lives in registers (wave-uniform per half); all reductions are
// DPP+readlane (ALU-only). LDS is used ONLY for the genuine 32-lane
// transposes (hidden-layer broadcasts).
__global__ __attribute__((amdgpu_flat_work_group_size(64, 64)))
__attribute__((amdgpu_waves_per_eu(2, 2))) void reac_kernel(
    const float* __restrict__ useq,   // [B][T] f32
    const float* __restrict__ xz0,    // [B][26] f32
    const float* __restrict__ r1W0, const float* __restrict__ r1b0,
    const float* __restrict__ r1W1, const float* __restrict__ r1b1,
    const float* __restrict__ r1W2, const float* __restrict__ r1b2,
    const float* __restrict__ r2W0, const float* __restrict__ r2b0,
    const float* __restrict__ r2W1, const float* __restrict__ r2b1,
    const float* __restrict__ r2W2, const float* __restrict__ r2b2,
    const float* __restrict__ r3W0, const float* __restrict__ r3b0,
    const float* __restrict__ r3W1, const float* __restrict__ r3b1,
    const float* __restrict__ r3W2, const float* __restrict__ r3b2,
    float2* __restrict__ out)         // [B][T] -> (x0,x1) f32
{
  const int lane = threadIdx.x;
  const int j = lane & 31;
  const bool hi = lane >= 32;            // element selector within wave
  const int b = blockIdx.x;
  const int ge = 2 * b + (hi ? 1 : 0);   // global element index

  // ---- weights (column j), tanh prescale KE folded in ----
  float w0K1 = r1W0[j] * KE, b0K1 = r1b0[j] * KE;
  float w0K2 = r2W0[j] * KE, b0K2 = r2b0[j] * KE;
  float b1K1 = r1b1[j] * KE, b1K2 = r2b1[j] * KE;
  float w2s1 = r1W2[j] * 0.3f, w2s2 = r2W2[j] * 0.2f;

  v2f W1a[16], W1b[16];
#pragma unroll
  for (int k = 0; k < 16; ++k) {
    W1a[k] = mk2(r1W1[(2 * k) * 32 + j] * KE, r1W1[(2 * k + 1) * 32 + j] * KE);
    W1b[k] = mk2(r2W1[(2 * k) * 32 + j] * KE, r2W1[(2 * k + 1) * 32 + j] * KE);
  }

  // r3 layer-0: WZ[m] = rows (2m,2m+1) (x-part); WU[m] = rows (16+2m,17+2m).
  v2f WZ[8], WU[4];
#pragma unroll
  for (int m = 0; m < 8; ++m)
    WZ[m] = mk2(r3W0[(2 * m) * 32 + j] * KE, r3W0[(2 * m + 1) * 32 + j] * KE);
#pragma unroll
  for (int m = 0; m < 4; ++m)
    WU[m] = mk2(r3W0[(16 + 2 * m) * 32 + j] * KE,
                r3W0[(17 + 2 * m) * 32 + j] * KE);

  v2f W1C[16];
#pragma unroll
  for (int k = 0; k < 16; ++k)
    W1C[k] = mk2(r3W1[(2 * k) * 32 + j] * KE, r3W1[(2 * k + 1) * 32 + j] * KE);
  float b0CK = r3b0[j] * KE, b1CK = r3b1[j] * KE;
  float w2C02 = r3W2[j] * 0.2f;

  // wave-uniform scalars (biases folded with output scales)
  const float b2sA = r1b2[0] * 0.3f;
  const float b2sB = r2b2[0] * 0.2f;
  const float b2Cs = r3b2[0] * 0.2f - 0.05f;   // folds -F/V*0.5 of dCb

  __shared__ __align__(16) float h12s[2][2][32];  // [elem][net][neuron]
  __shared__ __align__(16) float hR3s[2][3][32];  // [elem][z,z23,z4][neuron]

  float* h12a = &h12s[hi ? 1 : 0][0][0];
  float* h12b = h12a + 32;
  float* hR3e = &hR3s[hi ? 1 : 0][0][0];

  float x0 = xz0[ge * 26 + 0];
  float x1 = xz0[ge * 26 + 1];
  // z-state in registers; wave-uniform per half. All indices static.
  float z[24];
#pragma unroll
  for (int i = 0; i < 24; ++i) z[i] = xz0[ge * 26 + 2 + i];

  // r3 layer-0 over register z: full A(z) and the A(z4)-prefix (all terms
  // except (x0,x1).WZ[7]). Term->accumulator assignment identical to the
  // validated LDS version (bit-identical results).
  auto r3_l0 = [&](float& AzO, float& A4pO) {
    v2f pa = mk2(b0CK, 0.f), pb = mk2(0.f, 0.f);
    pa = pkfma(mk2(z[0], z[1]), WZ[0], pa);
    pb = pkfma(mk2(z[2], z[3]), WZ[1], pb);
    pa = pkfma(mk2(z[4], z[5]), WZ[2], pa);
    pb = pkfma(mk2(z[6], z[7]), WZ[3], pb);
    pa = pkfma(mk2(z[8], z[9]), WZ[4], pa);
    pb = pkfma(mk2(z[10], z[11]), WZ[5], pb);
    pa = pkfma(mk2(z[12], z[13]), WZ[6], pa);
    pb = pkfma(mk2(z[14], z[15]), WZ[7], pb);
    pa = pkfma(mk2(z[16], z[17]), WU[0], pa);
    pb = pkfma(mk2(z[18], z[19]), WU[1], pb);
    pa = pkfma(mk2(z[20], z[21]), WU[2], pa);
    pb = pkfma(mk2(z[22], z[23]), WU[3], pb);
    v2f s = pa + pb;
    AzO = s.x + s.y;
    v2f qa = mk2(b0CK, 0.f), qb = mk2(0.f, 0.f);
    qa = pkfma(mk2(z[2], z[3]), WZ[0], qa);
    qb = pkfma(mk2(z[4], z[5]), WZ[1], qb);
    qa = pkfma(mk2(z[6], z[7]), WZ[2], qa);
    qb = pkfma(mk2(z[8], z[9]), WZ[3], qb);
    qa = pkfma(mk2(z[10], z[11]), WZ[4], qa);
    qb = pkfma(mk2(z[12], z[13]), WZ[5], qb);
    qa = pkfma(mk2(z[14], z[15]), WZ[6], qa);
    qb = pkfma(mk2(z[16], z[17]), WU[0], qb);
    qa = pkfma(mk2(z[18], z[19]), WU[1], qa);
    qb = pkfma(mk2(z[20], z[21]), WU[2], qb);
    qa = pkfma(mk2(z[22], z[23]), WU[3], qa);
    v2f s2 = qa + qb;
    A4pO = s2.x + s2.y;
  };

  // RK stage finish: both nets' layer-1 outputs already in a1,a2.
  auto stage_finish = [&](float a1, float a2, float sx, float sy, float rc,
                          float CafF, float& kx, float& ky) {
    float ra = elem_total_sel(tanh_pre(a1) * w2s1, hi) + b2sA;  // r1
    float rb = elem_total_sel(tanh_pre(a2) * w2s2, hi) + b2sB;  // r2
    float dCa = fmaf(-0.03f, sx, CafF) - ra;
    float dCb = fmaf(-0.02f, sy, fmaf(-3.0f, rb, ra) + rc);
    kx = dCa * (1.0f / 0.3f);
    ky = dCb * (1.0f / 0.2f);
  };

  // ---- prologue: pipeline state for t=0 ----
  float Az, A4p;           // carried A(z_t) and A(z4_t)-prefix
  r3_l0(Az, A4p);
  {
    float h0 = tanh_pre(Az);
    CFENCE();
    hR3e[j] = h0;          // h(z_0)
    CFENCE();
  }
  float o0 = dot32(hR3e, W1C, b1CK);
  float rc1 = elem_total_sel(tanh_pre(o0) * w2C02, hi) + b2Cs;

  const float* up = useq + ge * TT;
  float2* outp = out + ge * TT;
  float u = up[0];

  for (int t = 0; t < TT; ++t) {
    int tn = (t < TT - 1) ? (t + 1) : t;
    float u_nxt = up[tn];              // prefetch, consumed next iter
    float CafF = fmaf(u, 0.05f, 0.05f);

    if (j == 0) outp[t] = make_float2(x0, x1);

    // R0: z4 completion + z23 by linearity; h(z23), h(z4); stage-1 hiddens.
    float A4 = fmaf(x1, WZ[7].y, fmaf(x0, WZ[7].x, A4p));
    float A23 = 0.5f * (Az + A4);
    float h23 = tanh_pre(A23);
    float h4v = tanh_pre(A4);
    float g1a = tanh_pre(fmaf(x0, w0K1, b0K1));
    float g1b = tanh_pre(fmaf(x1, w0K2, b0K2));
    CFENCE();
    // R1: LDS broadcasts
    h12a[j] = g1a;
    h12b[j] = g1b;
    hR3e[32 + j] = h23;
    hR3e[64 + j] = h4v;
    CFENCE();
    // R2: stage-1 finish + rc23/rc4 + stage-2 hiddens (4 indep dots)
    float a1 = dot32(h12a, W1a, b1K1);
    float a2 = dot32(h12b, W1b, b1K2);
    float o1 = dot32(hR3e + 32, W1C, b1CK);
    float o2 = dot32(hR3e + 64, W1C, b1CK);
    float rc23 = elem_total_sel(tanh_pre(o1) * w2C02, hi) + b2Cs;
    float rc4  = elem_total_sel(tanh_pre(o2) * w2C02, hi) + b2Cs;
    float kx1, ky1;
    stage_finish(a1, a2, x0, x1, rc1, CafF, kx1, ky1);
    float sx2 = fmaf(kx1, 0.5f, x0), sy2 = fmaf(ky1, 0.5f, x1);
    float g2a = tanh_pre(fmaf(sx2, w0K1, b0K1));
    float g2b = tanh_pre(fmaf(sy2, w0K2, b0K2));
    CFENCE();
    // R3
    h12a[j] = g2a;
    h12b[j] = g2b;
    CFENCE();
    // R4: stage-2 finish (register z-shift interleaves freely here)
    float a1_2 = dot32(h12a, W1a, b1K1);
    float a2_2 = dot32(h12b, W1b, b1K2);
    float kx2, ky2;
    stage_finish(a1_2, a2_2, sx2, sy2, rc23, CafF, kx2, ky2);
    // zplus = [z[2:16], x0, x1, z[17:24], u] — static-index register shift
#pragma unroll
    for (int i = 0; i < 14; ++i) z[i] = z[i + 2];
    z[14] = x0;
    z[15] = x1;
#pragma unroll
    for (int i = 16; i < 23; ++i) z[i] = z[i + 1];
    z[23] = u;
    float sx3 = fmaf(kx2, 0.5f, x0), sy3 = fmaf(ky2, 0.5f, x1);
    float g3a = tanh_pre(fmaf(sx3, w0K1, b0K1));
    float g3b = tanh_pre(fmaf(sy3, w0K2, b0K2));
    CFENCE();
    // R5
    h12a[j] = g3a;
    h12b[j] = g3b;
    CFENCE();
    // R6: stage-3 finish || next-step r3 layer-0 (register math)
    float a1_3 = dot32(h12a, W1a, b1K1);
    float a2_3 = dot32(h12b, W1b, b1K2);
    float Azn, A4pn;
    r3_l0(Azn, A4pn);
    float kx3, ky3;
    stage_finish(a1_3, a2_3, sx3, sy3, rc23, CafF, kx3, ky3);
    float sx4 = x0 + kx3, sy4 = x1 + ky3;
    float g4a = tanh_pre(fmaf(sx4, w0K1, b0K1));
    float g4b = tanh_pre(fmaf(sy4, w0K2, b0K2));
    float h0n = tanh_pre(Azn);
    CFENCE();
    // R7
    h12a[j] = g4a;
    h12b[j] = g4b;
    hR3e[j] = h0n;            // h(z_{t+1})
    CFENCE();
    // R8: stage-4 finish + rc1 for t+1 + state update
    float a1_4 = dot32(h12a, W1a, b1K1);
    float a2_4 = dot32(h12b, W1b, b1K2);
    float o0n = dot32(hR3e, W1C, b1CK);
    float kx4, ky4;
    stage_finish(a1_4, a2_4, sx4, sy4, rc4, CafF, kx4, ky4);
    rc1 = elem_total_sel(tanh_pre(o0n) * w2C02, hi) + b2Cs;
    x0 += (kx1 + 2.0f * (kx2 + kx3) + kx4) * (1.0f / 6.0f);
    x1 += (ky1 + 2.0f * (ky2 + ky3) + ky4) * (1.0f / 6.0f);
    Az = Azn;
    A4p = A4pn;
    u = u_nxt;
    CFENCE();
  }
}

extern "C" void kernel_launch(void* const* d_in, const int* in_sizes, int n_in,
                              void* d_out, int out_size, void* d_ws, size_t ws_size,
                              hipStream_t stream) {
  const float* p[20];
  for (int i = 0; i < 20; ++i) p[i] = (const float*)d_in[i];
  reac_kernel<<<dim3(2048), dim3(64), 0, stream>>>(
      p[0], p[1], p[2], p[3], p[4], p[5], p[6], p[7], p[8], p[9], p[10],
      p[11], p[12], p[13], p[14], p[15], p[16], p[17], p[18], p[19],
      (float2*)d_out);
}